// Round 8
// baseline (324.589 us; speedup 1.0000x reference)
//
#include <hip/hip_runtime.h>
#include <hip/hip_bf16.h>

#define N_NODES 50000
#define N_EDGES 800000
#define F 128
#define NC 41
#define SCAN_BLK 256
#define N_SCAN_BLKS ((N_NODES + SCAN_BLK - 1) / SCAN_BLK)   // 196
#define NSLICE 8
#define SLICE_NODES (N_NODES / NSLICE)   // 6250 exactly
#define FILL_BLKS_PER_SLICE 64

typedef __attribute__((ext_vector_type(4))) float f32x4;
typedef __attribute__((ext_vector_type(8))) short bf16x8;   // 8 bf16 = 4 VGPRs

__device__ __forceinline__ float bf2f(unsigned short u) {
    unsigned int x = ((unsigned int)u) << 16;
    return __uint_as_float(x);
}
__device__ __forceinline__ unsigned short f2bf(float f) {
    unsigned int x = __float_as_uint(f);
    unsigned int lsb = (x >> 16) & 1u;
    x += 0x7fffu + lsb;
    return (unsigned short)(x >> 16);
}

__global__ void zero_deg_kernel(int* deg) {
    int i = blockIdx.x * blockDim.x + threadIdx.x;
    if (i < N_NODES) deg[i] = 0;
}

__global__ void count_deg_kernel(const int* __restrict__ dst, int* __restrict__ deg) {
    int e = blockIdx.x * blockDim.x + threadIdx.x;
    if (e < N_EDGES) {
        int d = __builtin_nontemporal_load(&dst[e]);
        atomicAdd(&deg[d], 1);
    }
}

__global__ __launch_bounds__(SCAN_BLK) void scan1_kernel(const int* __restrict__ deg,
                                                         int* __restrict__ local,
                                                         int* __restrict__ bsum) {
    __shared__ int buf[SCAN_BLK];
    int tid = threadIdx.x;
    int i = blockIdx.x * SCAN_BLK + tid;
    int v = (i < N_NODES) ? deg[i] : 0;
    buf[tid] = v;
    __syncthreads();
#pragma unroll
    for (int off = 1; off < SCAN_BLK; off <<= 1) {
        int t = (tid >= off) ? buf[tid - off] : 0;
        __syncthreads();
        buf[tid] += t;
        __syncthreads();
    }
    if (i < N_NODES) local[i] = buf[tid] - v;
    if (tid == SCAN_BLK - 1) bsum[blockIdx.x] = buf[tid];
}

__global__ __launch_bounds__(SCAN_BLK) void scan2_kernel(int* __restrict__ bsum,
                                                         int* __restrict__ row_ptr) {
    __shared__ int buf[SCAN_BLK];
    int tid = threadIdx.x;
    int v = (tid < N_SCAN_BLKS) ? bsum[tid] : 0;
    buf[tid] = v;
    __syncthreads();
#pragma unroll
    for (int off = 1; off < SCAN_BLK; off <<= 1) {
        int t = (tid >= off) ? buf[tid - off] : 0;
        __syncthreads();
        buf[tid] += t;
        __syncthreads();
    }
    if (tid < N_SCAN_BLKS) bsum[tid] = buf[tid] - v;
    if (tid == SCAN_BLK - 1) row_ptr[N_NODES] = buf[tid];
}

__global__ __launch_bounds__(SCAN_BLK) void scan3_kernel(const int* __restrict__ deg,
                                                         const int* __restrict__ local,
                                                         const int* __restrict__ bsum,
                                                         int* __restrict__ row_ptr,
                                                         int* __restrict__ cursor,
                                                         float* __restrict__ inv_deg) {
    int i = blockIdx.x * SCAN_BLK + threadIdx.x;
    if (i < N_NODES) {
        int rp = local[i] + bsum[blockIdx.x];
        row_ptr[i] = rp;
        cursor[i] = rp;
        inv_deg[i] = 1.0f / fmaxf((float)deg[i], 1.0f);
    }
}

// XCD-sliced CSR fill with non-temporal edge reads: slice = blockIdx & 7 keeps each csr
// line on one XCD; nt loads mark the streamed dst/src evict-first so the dirty csr lines
// stay resident in L2 until full (kills the ~9x writeback amplification).
__global__ __launch_bounds__(256) void fill_csr_sliced_kernel(const int* __restrict__ src,
                                                              const int* __restrict__ dst,
                                                              int* __restrict__ cursor,
                                                              int* __restrict__ csr_src) {
    int slice = blockIdx.x & (NSLICE - 1);
    int bid = blockIdx.x >> 3;              // block index within slice
    int lo = slice * SLICE_NODES, hi = lo + SLICE_NODES;
    int stride = FILL_BLKS_PER_SLICE * 256;
    for (int e = bid * 256 + threadIdx.x; e < N_EDGES; e += stride) {
        int d = __builtin_nontemporal_load(&dst[e]);
        if (d >= lo && d < hi) {
            int p = atomicAdd(&cursor[d], 1);
            int s = __builtin_nontemporal_load(&src[e]);
            csr_src[p] = s;
        }
    }
}

// Pack GEMM-A weights into MFMA B-fragment order (bf16).
// Bpk[((ct*4+kb)*64+l)*8+j] = W[k][c], k=kb*32+(l>>4)*8+j, c=ct*16+(l&15).
// Logical W[128][256] = [W_self0 | W_neigh0].
__global__ void pack_w0_kernel(const float* __restrict__ Ws, const float* __restrict__ Wn,
                               unsigned short* __restrict__ Bpk) {
    int i = blockIdx.x * blockDim.x + threadIdx.x;
    if (i >= 128 * 256) return;
    int j = i & 7, l = (i >> 3) & 63, kb = (i >> 9) & 3, ct = i >> 11;
    int k = kb * 32 + (l >> 4) * 8 + j;
    int c = ct * 16 + (l & 15);
    float v = (c < F) ? Ws[k * F + c] : Wn[k * F + (c - F)];
    Bpk[i] = f2bf(v);
}

// Pack GEMM-B weights: logical W[128][128], cols 0..40 = W_self1, 64..104 = W_neigh1, else 0.
__global__ void pack_w1_kernel(const float* __restrict__ Ws, const float* __restrict__ Wn,
                               unsigned short* __restrict__ Bpk) {
    int i = blockIdx.x * blockDim.x + threadIdx.x;
    if (i >= 128 * 128) return;
    int j = i & 7, l = (i >> 3) & 63, kb = (i >> 9) & 3, ct = i >> 11;
    int k = kb * 32 + (l >> 4) * 8 + j;
    int c = ct * 16 + (l & 15);
    float v = 0.0f;
    if (c < 48) { if (c < NC) v = Ws[k * NC + c]; }
    else if (c >= 64 && c < 112) { int cc = c - 64; if (cc < NC) v = Wn[k * NC + cc]; }
    Bpk[i] = f2bf(v);
}

// MFMA GEMM: C[M][4*CT*16] = A[M][128] @ W. 64-row tile/block, 4 waves, wave covers CT*16 cols.
// AF32: A is fp32 (converted to bf16 during LDS staging); else A is bf16.
// MODE 0: write all cols bf16 to outA[M][CT*64].
// MODE 1 (CT=2): cols<48 -> outA[M][48], 64<=c<112 -> outB[M][48] (both bf16).
template<bool AF32, int CT, int MODE>
__global__ __launch_bounds__(256) void gemm_mfma_kernel(const void* __restrict__ Av,
                                                        const unsigned short* __restrict__ Bpk,
                                                        int M,
                                                        unsigned short* __restrict__ outA,
                                                        unsigned short* __restrict__ outB) {
    __shared__ unsigned short As[64 * 128];  // bf16, XOR-swizzled: idx ^= (row&7)<<3
    int tid = threadIdx.x;
    int wave = tid >> 6, lane = tid & 63;
    int row0 = blockIdx.x * 64;

    if (AF32) {
        const float* A = (const float*)Av;
#pragma unroll
        for (int i = 0; i < 8; ++i) {
            int fid = tid + i * 256;            // float4 id: 2048 total (64 rows x 32)
            int row = fid >> 5, c4 = (fid & 31) * 4;
            int grow = row0 + row; if (grow > M - 1) grow = M - 1;
            f32x4 v = *(const f32x4*)(A + (size_t)grow * F + c4);
            unsigned int p0 = (unsigned)f2bf(v.x) | ((unsigned)f2bf(v.y) << 16);
            unsigned int p1 = (unsigned)f2bf(v.z) | ((unsigned)f2bf(v.w) << 16);
            int idx = (row * 128 + c4) ^ ((row & 7) << 3);
            *(uint2*)&As[idx] = make_uint2(p0, p1);
        }
    } else {
        const unsigned short* A = (const unsigned short*)Av;
#pragma unroll
        for (int i = 0; i < 4; ++i) {
            int fid = tid + i * 256;            // uint4 id: 1024 total (64 rows x 16 chunks of 8 bf16)
            int row = fid >> 4, c8 = (fid & 15) * 8;
            int grow = row0 + row; if (grow > M - 1) grow = M - 1;
            uint4 v = *(const uint4*)&A[(size_t)grow * F + c8];
            int idx = (row * 128 + c8) ^ ((row & 7) << 3);
            *(uint4*)&As[idx] = v;
        }
    }
    __syncthreads();

    f32x4 acc[4][CT];
#pragma unroll
    for (int m = 0; m < 4; ++m)
#pragma unroll
        for (int n = 0; n < CT; ++n) acc[m][n] = (f32x4){0.f, 0.f, 0.f, 0.f};

#pragma unroll
    for (int kb = 0; kb < 4; ++kb) {
        bf16x8 afr[4];
#pragma unroll
        for (int m = 0; m < 4; ++m) {
            int row = m * 16 + (lane & 15);
            int ke = kb * 32 + (lane >> 4) * 8;
            int idx = (row * 128 + ke) ^ ((row & 7) << 3);
            afr[m] = *(const bf16x8*)&As[idx];
        }
#pragma unroll
        for (int n = 0; n < CT; ++n) {
            int ct = wave * CT + n;
            bf16x8 bfr = *(const bf16x8*)&Bpk[((ct * 4 + kb) * 64 + lane) * 8];
#pragma unroll
            for (int m = 0; m < 4; ++m)
                acc[m][n] = __builtin_amdgcn_mfma_f32_16x16x32_bf16(afr[m], bfr, acc[m][n], 0, 0, 0);
        }
    }

#pragma unroll
    for (int m = 0; m < 4; ++m) {
#pragma unroll
        for (int i = 0; i < 4; ++i) {
            int r = row0 + m * 16 + (lane >> 4) * 4 + i;
            if (r < M) {
#pragma unroll
                for (int n = 0; n < CT; ++n) {
                    int c = (wave * CT + n) * 16 + (lane & 15);
                    unsigned short val = f2bf(acc[m][n][i]);
                    if (MODE == 0) {
                        outA[(size_t)r * (CT * 64) + c] = val;
                    } else {
                        if (c < 48) outA[(size_t)r * 48 + c] = val;
                        else if (c >= 64 && c < 112) outB[(size_t)r * 48 + (c - 64)] = val;
                    }
                }
            }
        }
    }
}

// h[node] = relu(u_self + mean(u_neigh) + b0); u is bf16 [N][256] (self cols 0..127, neigh 128..255).
// One wave/node; lane t handles 2 cols via uint. h written bf16 [N][128].
__global__ __launch_bounds__(64) void agg0_kernel(const unsigned int* __restrict__ u,
                                                  const int* __restrict__ row_ptr,
                                                  const int* __restrict__ csr_src,
                                                  const float* __restrict__ inv_deg,
                                                  const float* __restrict__ b0,
                                                  unsigned int* __restrict__ hu) {
    int node = blockIdx.x;
    int t = threadIdx.x;
    int s = row_ptr[node], e = row_ptr[node + 1];
    float ax = 0.f, ay = 0.f;
    for (int j = s; j < e; ++j) {
        int sr = csr_src[j];
        unsigned int v = u[(size_t)sr * 128 + 64 + t];
        ax += bf2f((unsigned short)(v & 0xffffu));
        ay += bf2f((unsigned short)(v >> 16));
    }
    float inv = inv_deg[node];
    unsigned int vs = u[(size_t)node * 128 + t];
    float2 bb = ((const float2*)b0)[t];
    float h0 = fmaxf(bf2f((unsigned short)(vs & 0xffffu)) + ax * inv + bb.x, 0.0f);
    float h1 = fmaxf(bf2f((unsigned short)(vs >> 16)) + ay * inv + bb.y, 0.0f);
    hu[(size_t)node * 64 + t] = (unsigned)f2bf(h0) | ((unsigned)f2bf(h1) << 16);
}

// out[node][c] = t_self[node][c] + b1[c] + mean(t_neigh[src][c]); t_* bf16 [N][48].
__global__ __launch_bounds__(64) void final_out_kernel(const unsigned int* __restrict__ ts,
                                                       const unsigned int* __restrict__ tn,
                                                       const int* __restrict__ row_ptr,
                                                       const int* __restrict__ csr_src,
                                                       const float* __restrict__ inv_deg,
                                                       const float* __restrict__ b1,
                                                       float* __restrict__ out) {
    int node = blockIdx.x;
    int c = threadIdx.x;  // active 0..23
    if (c >= 24) return;
    int s = row_ptr[node], e = row_ptr[node + 1];
    float ax = 0.f, ay = 0.f;
    for (int j = s; j < e; ++j) {
        int sr = csr_src[j];
        unsigned int v = tn[(size_t)sr * 24 + c];
        ax += bf2f((unsigned short)(v & 0xffffu));
        ay += bf2f((unsigned short)(v >> 16));
    }
    float inv = inv_deg[node];
    unsigned int vs = ts[(size_t)node * 24 + c];
    int c0 = 2 * c, c1 = 2 * c + 1;
    if (c0 < NC)
        out[(size_t)node * NC + c0] = bf2f((unsigned short)(vs & 0xffffu)) + b1[c0] + ax * inv;
    if (c1 < NC)
        out[(size_t)node * NC + c1] = bf2f((unsigned short)(vs >> 16)) + b1[c1] + ay * inv;
}

extern "C" void kernel_launch(void* const* d_in, const int* in_sizes, int n_in,
                              void* d_out, int out_size, void* d_ws, size_t ws_size,
                              hipStream_t stream) {
    const float* x   = (const float*)d_in[0];
    const int*   src = (const int*)d_in[1];
    const int*   dst = (const int*)d_in[2];
    const float* Ws0 = (const float*)d_in[3];
    const float* Wn0 = (const float*)d_in[4];
    const float* b0  = (const float*)d_in[5];
    const float* Ws1 = (const float*)d_in[6];
    const float* Wn1 = (const float*)d_in[7];
    const float* b1  = (const float*)d_in[8];
    float* out = (float*)d_out;

    char* ws = (char*)d_ws;
    size_t o = 0;
    auto alloc = [&](size_t bytes) {
        size_t r = o;
        o = (o + bytes + 255) & ~(size_t)255;
        return r;
    };
    int*   deg     = (int*)(ws + alloc(sizeof(int) * N_NODES));
    int*   local   = (int*)(ws + alloc(sizeof(int) * N_NODES));
    int*   bsum    = (int*)(ws + alloc(sizeof(int) * N_SCAN_BLKS));
    int*   row_ptr = (int*)(ws + alloc(sizeof(int) * (N_NODES + 1)));
    int*   cursor  = (int*)(ws + alloc(sizeof(int) * N_NODES));
    int*   csr     = (int*)(ws + alloc(sizeof(int) * N_EDGES));
    float* inv_deg = (float*)(ws + alloc(sizeof(float) * N_NODES));
    unsigned short* Bpk0 = (unsigned short*)(ws + alloc(sizeof(short) * 128 * 256));
    unsigned short* Bpk1 = (unsigned short*)(ws + alloc(sizeof(short) * 128 * 128));
    unsigned short* u    = (unsigned short*)(ws + alloc(sizeof(short) * (size_t)N_NODES * 256));
    unsigned short* h    = (unsigned short*)(ws + alloc(sizeof(short) * (size_t)N_NODES * 128));
    unsigned short* t_self  = (unsigned short*)(ws + alloc(sizeof(short) * (size_t)N_NODES * 48));
    unsigned short* t_neigh = (unsigned short*)(ws + alloc(sizeof(short) * (size_t)N_NODES * 48));

    zero_deg_kernel<<<(N_NODES + 255) / 256, 256, 0, stream>>>(deg);
    count_deg_kernel<<<(N_EDGES + 255) / 256, 256, 0, stream>>>(dst, deg);
    scan1_kernel<<<N_SCAN_BLKS, SCAN_BLK, 0, stream>>>(deg, local, bsum);
    scan2_kernel<<<1, SCAN_BLK, 0, stream>>>(bsum, row_ptr);
    scan3_kernel<<<N_SCAN_BLKS, SCAN_BLK, 0, stream>>>(deg, local, bsum, row_ptr, cursor, inv_deg);
    fill_csr_sliced_kernel<<<NSLICE * FILL_BLKS_PER_SLICE, 256, 0, stream>>>(src, dst, cursor, csr);
    pack_w0_kernel<<<(128 * 256 + 255) / 256, 256, 0, stream>>>(Ws0, Wn0, Bpk0);
    pack_w1_kernel<<<(128 * 128 + 255) / 256, 256, 0, stream>>>(Ws1, Wn1, Bpk1);

    int nblk = (N_NODES + 63) / 64;  // 782
    // GEMM A: u = bf16(x) @ [Ws0|Wn0]  -> u bf16 [N][256]
    gemm_mfma_kernel<true, 4, 0><<<nblk, 256, 0, stream>>>(x, Bpk0, N_NODES, u, nullptr);
    // agg0: h = relu(u_self + mean(u_neigh) + b0) -> bf16 [N][128]
    agg0_kernel<<<N_NODES, 64, 0, stream>>>((const unsigned int*)u, row_ptr, csr, inv_deg, b0,
                                            (unsigned int*)h);
    // GEMM B: t = h @ Wcat1 -> t_self bf16[N][48], t_neigh bf16[N][48]
    gemm_mfma_kernel<false, 2, 1><<<nblk, 256, 0, stream>>>(h, Bpk1, N_NODES, t_self, t_neigh);
    // final: out = t_self + b1 + mean(t_neigh)
    final_out_kernel<<<N_NODES, 64, 0, stream>>>((const unsigned int*)t_self,
                                                 (const unsigned int*)t_neigh,
                                                 row_ptr, csr, inv_deg, b1, out);
}

// Round 9
// 290.803 us; speedup vs baseline: 1.1162x; 1.1162x over previous
//
#include <hip/hip_runtime.h>
#include <hip/hip_bf16.h>

#define N_NODES 50000
#define N_EDGES 800000
#define F 128
#define NC 41
#define SCAN_BLK 256
#define N_SCAN_BLKS ((N_NODES + SCAN_BLK - 1) / SCAN_BLK)   // 196
#define NSLICE 8
#define SLICE_NODES (N_NODES / NSLICE)   // 6250 exactly
#define FILL_BLKS_PER_SLICE 256

typedef __attribute__((ext_vector_type(4))) float f32x4;
typedef __attribute__((ext_vector_type(8))) short bf16x8;   // 8 bf16 = 4 VGPRs

__device__ __forceinline__ float bf2f(unsigned short u) {
    unsigned int x = ((unsigned int)u) << 16;
    return __uint_as_float(x);
}
__device__ __forceinline__ unsigned short f2bf(float f) {
    unsigned int x = __float_as_uint(f);
    unsigned int lsb = (x >> 16) & 1u;
    x += 0x7fffu + lsb;
    return (unsigned short)(x >> 16);
}

__global__ void zero_deg_kernel(int* deg) {
    int i = blockIdx.x * blockDim.x + threadIdx.x;
    if (i < N_NODES) deg[i] = 0;
}

__global__ void count_deg_kernel(const int* __restrict__ dst, int* __restrict__ deg) {
    int e = blockIdx.x * blockDim.x + threadIdx.x;
    if (e < N_EDGES) atomicAdd(&deg[dst[e]], 1);
}

__global__ __launch_bounds__(SCAN_BLK) void scan1_kernel(const int* __restrict__ deg,
                                                         int* __restrict__ local,
                                                         int* __restrict__ bsum) {
    __shared__ int buf[SCAN_BLK];
    int tid = threadIdx.x;
    int i = blockIdx.x * SCAN_BLK + tid;
    int v = (i < N_NODES) ? deg[i] : 0;
    buf[tid] = v;
    __syncthreads();
#pragma unroll
    for (int off = 1; off < SCAN_BLK; off <<= 1) {
        int t = (tid >= off) ? buf[tid - off] : 0;
        __syncthreads();
        buf[tid] += t;
        __syncthreads();
    }
    if (i < N_NODES) local[i] = buf[tid] - v;
    if (tid == SCAN_BLK - 1) bsum[blockIdx.x] = buf[tid];
}

__global__ __launch_bounds__(SCAN_BLK) void scan2_kernel(int* __restrict__ bsum,
                                                         int* __restrict__ row_ptr) {
    __shared__ int buf[SCAN_BLK];
    int tid = threadIdx.x;
    int v = (tid < N_SCAN_BLKS) ? bsum[tid] : 0;
    buf[tid] = v;
    __syncthreads();
#pragma unroll
    for (int off = 1; off < SCAN_BLK; off <<= 1) {
        int t = (tid >= off) ? buf[tid - off] : 0;
        __syncthreads();
        buf[tid] += t;
        __syncthreads();
    }
    if (tid < N_SCAN_BLKS) bsum[tid] = buf[tid] - v;
    if (tid == SCAN_BLK - 1) row_ptr[N_NODES] = buf[tid];
}

__global__ __launch_bounds__(SCAN_BLK) void scan3_kernel(const int* __restrict__ deg,
                                                         const int* __restrict__ local,
                                                         const int* __restrict__ bsum,
                                                         int* __restrict__ row_ptr,
                                                         int* __restrict__ cursor,
                                                         float* __restrict__ inv_deg) {
    int i = blockIdx.x * SCAN_BLK + threadIdx.x;
    if (i < N_NODES) {
        int rp = local[i] + bsum[blockIdx.x];
        row_ptr[i] = rp;
        cursor[i] = rp;
        inv_deg[i] = 1.0f / fmaxf((float)deg[i], 1.0f);
    }
}

// XCD-sliced CSR fill: slice = blockIdx & 7 -> (round-robin dispatch) one XCD per slice.
// 2048 blocks (8/CU) for full occupancy to hide the load->atomic latency chain.
__global__ __launch_bounds__(256) void fill_csr_sliced_kernel(const int* __restrict__ src,
                                                              const int* __restrict__ dst,
                                                              int* __restrict__ cursor,
                                                              int* __restrict__ csr_src) {
    int slice = blockIdx.x & (NSLICE - 1);
    int bid = blockIdx.x >> 3;              // block index within slice
    int lo = slice * SLICE_NODES, hi = lo + SLICE_NODES;
    int stride = FILL_BLKS_PER_SLICE * 256;
    for (int e = bid * 256 + threadIdx.x; e < N_EDGES; e += stride) {
        int d = dst[e];
        if (d >= lo && d < hi) {
            int p = atomicAdd(&cursor[d], 1);
            csr_src[p] = src[e];
        }
    }
}

// Pack GEMM-A weights into MFMA B-fragment order (bf16).
// Bpk[((ct*4+kb)*64+l)*8+j] = W[k][c], k=kb*32+(l>>4)*8+j, c=ct*16+(l&15).
// Logical W[128][256] = [W_self0 | W_neigh0].
__global__ void pack_w0_kernel(const float* __restrict__ Ws, const float* __restrict__ Wn,
                               unsigned short* __restrict__ Bpk) {
    int i = blockIdx.x * blockDim.x + threadIdx.x;
    if (i >= 128 * 256) return;
    int j = i & 7, l = (i >> 3) & 63, kb = (i >> 9) & 3, ct = i >> 11;
    int k = kb * 32 + (l >> 4) * 8 + j;
    int c = ct * 16 + (l & 15);
    float v = (c < F) ? Ws[k * F + c] : Wn[k * F + (c - F)];
    Bpk[i] = f2bf(v);
}

// Pack GEMM-B weights: logical W[128][128], cols 0..40 = W_self1, 64..104 = W_neigh1, else 0.
__global__ void pack_w1_kernel(const float* __restrict__ Ws, const float* __restrict__ Wn,
                               unsigned short* __restrict__ Bpk) {
    int i = blockIdx.x * blockDim.x + threadIdx.x;
    if (i >= 128 * 128) return;
    int j = i & 7, l = (i >> 3) & 63, kb = (i >> 9) & 3, ct = i >> 11;
    int k = kb * 32 + (l >> 4) * 8 + j;
    int c = ct * 16 + (l & 15);
    float v = 0.0f;
    if (c < 48) { if (c < NC) v = Ws[k * NC + c]; }
    else if (c >= 64 && c < 112) { int cc = c - 64; if (cc < NC) v = Wn[k * NC + cc]; }
    Bpk[i] = f2bf(v);
}

// MFMA GEMM: C[M][4*CT*16] = A[M][128] @ W. 64-row tile/block, 4 waves, wave covers CT*16 cols.
// AF32: A is fp32 (converted to bf16 during LDS staging); else A is bf16.
// MODE 0: write all cols bf16 to outA[M][CT*64].
// MODE 1 (CT=2): cols<48 -> outA[M][48], 64<=c<112 -> outB[M][48] (both bf16).
template<bool AF32, int CT, int MODE>
__global__ __launch_bounds__(256) void gemm_mfma_kernel(const void* __restrict__ Av,
                                                        const unsigned short* __restrict__ Bpk,
                                                        int M,
                                                        unsigned short* __restrict__ outA,
                                                        unsigned short* __restrict__ outB) {
    __shared__ unsigned short As[64 * 128];  // bf16, XOR-swizzled: idx ^= (row&7)<<3
    int tid = threadIdx.x;
    int wave = tid >> 6, lane = tid & 63;
    int row0 = blockIdx.x * 64;

    if (AF32) {
        const float* A = (const float*)Av;
#pragma unroll
        for (int i = 0; i < 8; ++i) {
            int fid = tid + i * 256;            // float4 id: 2048 total (64 rows x 32)
            int row = fid >> 5, c4 = (fid & 31) * 4;
            int grow = row0 + row; if (grow > M - 1) grow = M - 1;
            f32x4 v = *(const f32x4*)(A + (size_t)grow * F + c4);
            unsigned int p0 = (unsigned)f2bf(v.x) | ((unsigned)f2bf(v.y) << 16);
            unsigned int p1 = (unsigned)f2bf(v.z) | ((unsigned)f2bf(v.w) << 16);
            int idx = (row * 128 + c4) ^ ((row & 7) << 3);
            *(uint2*)&As[idx] = make_uint2(p0, p1);
        }
    } else {
        const unsigned short* A = (const unsigned short*)Av;
#pragma unroll
        for (int i = 0; i < 4; ++i) {
            int fid = tid + i * 256;            // uint4 id: 1024 total (64 rows x 16 chunks of 8 bf16)
            int row = fid >> 4, c8 = (fid & 15) * 8;
            int grow = row0 + row; if (grow > M - 1) grow = M - 1;
            uint4 v = *(const uint4*)&A[(size_t)grow * F + c8];
            int idx = (row * 128 + c8) ^ ((row & 7) << 3);
            *(uint4*)&As[idx] = v;
        }
    }
    __syncthreads();

    f32x4 acc[4][CT];
#pragma unroll
    for (int m = 0; m < 4; ++m)
#pragma unroll
        for (int n = 0; n < CT; ++n) acc[m][n] = (f32x4){0.f, 0.f, 0.f, 0.f};

#pragma unroll
    for (int kb = 0; kb < 4; ++kb) {
        bf16x8 afr[4];
#pragma unroll
        for (int m = 0; m < 4; ++m) {
            int row = m * 16 + (lane & 15);
            int ke = kb * 32 + (lane >> 4) * 8;
            int idx = (row * 128 + ke) ^ ((row & 7) << 3);
            afr[m] = *(const bf16x8*)&As[idx];
        }
#pragma unroll
        for (int n = 0; n < CT; ++n) {
            int ct = wave * CT + n;
            bf16x8 bfr = *(const bf16x8*)&Bpk[((ct * 4 + kb) * 64 + lane) * 8];
#pragma unroll
            for (int m = 0; m < 4; ++m)
                acc[m][n] = __builtin_amdgcn_mfma_f32_16x16x32_bf16(afr[m], bfr, acc[m][n], 0, 0, 0);
        }
    }

#pragma unroll
    for (int m = 0; m < 4; ++m) {
#pragma unroll
        for (int i = 0; i < 4; ++i) {
            int r = row0 + m * 16 + (lane >> 4) * 4 + i;
            if (r < M) {
#pragma unroll
                for (int n = 0; n < CT; ++n) {
                    int c = (wave * CT + n) * 16 + (lane & 15);
                    unsigned short val = f2bf(acc[m][n][i]);
                    if (MODE == 0) {
                        outA[(size_t)r * (CT * 64) + c] = val;
                    } else {
                        if (c < 48) outA[(size_t)r * 48 + c] = val;
                        else if (c >= 64 && c < 112) outB[(size_t)r * 48 + (c - 64)] = val;
                    }
                }
            }
        }
    }
}

// h[node] = relu(u_self + mean(u_neigh) + b0); u is bf16 [N][256] (self cols 0..127, neigh 128..255).
// One wave/node; lane t handles 2 cols via uint. h written bf16 [N][128].
__global__ __launch_bounds__(64) void agg0_kernel(const unsigned int* __restrict__ u,
                                                  const int* __restrict__ row_ptr,
                                                  const int* __restrict__ csr_src,
                                                  const float* __restrict__ inv_deg,
                                                  const float* __restrict__ b0,
                                                  unsigned int* __restrict__ hu) {
    int node = blockIdx.x;
    int t = threadIdx.x;
    int s = row_ptr[node], e = row_ptr[node + 1];
    float ax = 0.f, ay = 0.f;
    for (int j = s; j < e; ++j) {
        int sr = csr_src[j];
        unsigned int v = u[(size_t)sr * 128 + 64 + t];
        ax += bf2f((unsigned short)(v & 0xffffu));
        ay += bf2f((unsigned short)(v >> 16));
    }
    float inv = inv_deg[node];
    unsigned int vs = u[(size_t)node * 128 + t];
    float2 bb = ((const float2*)b0)[t];
    float h0 = fmaxf(bf2f((unsigned short)(vs & 0xffffu)) + ax * inv + bb.x, 0.0f);
    float h1 = fmaxf(bf2f((unsigned short)(vs >> 16)) + ay * inv + bb.y, 0.0f);
    hu[(size_t)node * 64 + t] = (unsigned)f2bf(h0) | ((unsigned)f2bf(h1) << 16);
}

// out[node][c] = t_self[node][c] + b1[c] + mean(t_neigh[src][c]); t_* bf16 [N][48].
__global__ __launch_bounds__(64) void final_out_kernel(const unsigned int* __restrict__ ts,
                                                       const unsigned int* __restrict__ tn,
                                                       const int* __restrict__ row_ptr,
                                                       const int* __restrict__ csr_src,
                                                       const float* __restrict__ inv_deg,
                                                       const float* __restrict__ b1,
                                                       float* __restrict__ out) {
    int node = blockIdx.x;
    int c = threadIdx.x;  // active 0..23
    if (c >= 24) return;
    int s = row_ptr[node], e = row_ptr[node + 1];
    float ax = 0.f, ay = 0.f;
    for (int j = s; j < e; ++j) {
        int sr = csr_src[j];
        unsigned int v = tn[(size_t)sr * 24 + c];
        ax += bf2f((unsigned short)(v & 0xffffu));
        ay += bf2f((unsigned short)(v >> 16));
    }
    float inv = inv_deg[node];
    unsigned int vs = ts[(size_t)node * 24 + c];
    int c0 = 2 * c, c1 = 2 * c + 1;
    if (c0 < NC)
        out[(size_t)node * NC + c0] = bf2f((unsigned short)(vs & 0xffffu)) + b1[c0] + ax * inv;
    if (c1 < NC)
        out[(size_t)node * NC + c1] = bf2f((unsigned short)(vs >> 16)) + b1[c1] + ay * inv;
}

extern "C" void kernel_launch(void* const* d_in, const int* in_sizes, int n_in,
                              void* d_out, int out_size, void* d_ws, size_t ws_size,
                              hipStream_t stream) {
    const float* x   = (const float*)d_in[0];
    const int*   src = (const int*)d_in[1];
    const int*   dst = (const int*)d_in[2];
    const float* Ws0 = (const float*)d_in[3];
    const float* Wn0 = (const float*)d_in[4];
    const float* b0  = (const float*)d_in[5];
    const float* Ws1 = (const float*)d_in[6];
    const float* Wn1 = (const float*)d_in[7];
    const float* b1  = (const float*)d_in[8];
    float* out = (float*)d_out;

    char* ws = (char*)d_ws;
    size_t o = 0;
    auto alloc = [&](size_t bytes) {
        size_t r = o;
        o = (o + bytes + 255) & ~(size_t)255;
        return r;
    };
    int*   deg     = (int*)(ws + alloc(sizeof(int) * N_NODES));
    int*   local   = (int*)(ws + alloc(sizeof(int) * N_NODES));
    int*   bsum    = (int*)(ws + alloc(sizeof(int) * N_SCAN_BLKS));
    int*   row_ptr = (int*)(ws + alloc(sizeof(int) * (N_NODES + 1)));
    int*   cursor  = (int*)(ws + alloc(sizeof(int) * N_NODES));
    int*   csr     = (int*)(ws + alloc(sizeof(int) * N_EDGES));
    float* inv_deg = (float*)(ws + alloc(sizeof(float) * N_NODES));
    unsigned short* Bpk0 = (unsigned short*)(ws + alloc(sizeof(short) * 128 * 256));
    unsigned short* Bpk1 = (unsigned short*)(ws + alloc(sizeof(short) * 128 * 128));
    unsigned short* u    = (unsigned short*)(ws + alloc(sizeof(short) * (size_t)N_NODES * 256));
    unsigned short* h    = (unsigned short*)(ws + alloc(sizeof(short) * (size_t)N_NODES * 128));
    unsigned short* t_self  = (unsigned short*)(ws + alloc(sizeof(short) * (size_t)N_NODES * 48));
    unsigned short* t_neigh = (unsigned short*)(ws + alloc(sizeof(short) * (size_t)N_NODES * 48));

    zero_deg_kernel<<<(N_NODES + 255) / 256, 256, 0, stream>>>(deg);
    count_deg_kernel<<<(N_EDGES + 255) / 256, 256, 0, stream>>>(dst, deg);
    scan1_kernel<<<N_SCAN_BLKS, SCAN_BLK, 0, stream>>>(deg, local, bsum);
    scan2_kernel<<<1, SCAN_BLK, 0, stream>>>(bsum, row_ptr);
    scan3_kernel<<<N_SCAN_BLKS, SCAN_BLK, 0, stream>>>(deg, local, bsum, row_ptr, cursor, inv_deg);
    fill_csr_sliced_kernel<<<NSLICE * FILL_BLKS_PER_SLICE, 256, 0, stream>>>(src, dst, cursor, csr);
    pack_w0_kernel<<<(128 * 256 + 255) / 256, 256, 0, stream>>>(Ws0, Wn0, Bpk0);
    pack_w1_kernel<<<(128 * 128 + 255) / 256, 256, 0, stream>>>(Ws1, Wn1, Bpk1);

    int nblk = (N_NODES + 63) / 64;  // 782
    // GEMM A: u = bf16(x) @ [Ws0|Wn0]  -> u bf16 [N][256]
    gemm_mfma_kernel<true, 4, 0><<<nblk, 256, 0, stream>>>(x, Bpk0, N_NODES, u, nullptr);
    // agg0: h = relu(u_self + mean(u_neigh) + b0) -> bf16 [N][128]
    agg0_kernel<<<N_NODES, 64, 0, stream>>>((const unsigned int*)u, row_ptr, csr, inv_deg, b0,
                                            (unsigned int*)h);
    // GEMM B: t = h @ Wcat1 -> t_self bf16[N][48], t_neigh bf16[N][48]
    gemm_mfma_kernel<false, 2, 1><<<nblk, 256, 0, stream>>>(h, Bpk1, N_NODES, t_self, t_neigh);
    // final: out = t_self + b1 + mean(t_neigh)
    final_out_kernel<<<N_NODES, 64, 0, stream>>>((const unsigned int*)t_self,
                                                 (const unsigned int*)t_neigh,
                                                 row_ptr, csr, inv_deg, b1, out);
}

// Round 10
// 278.664 us; speedup vs baseline: 1.1648x; 1.0436x over previous
//
#include <hip/hip_runtime.h>
#include <hip/hip_bf16.h>

#define N_NODES 50000
#define N_EDGES 800000
#define F 128
#define NC 41
#define SCAN_BLK 256
#define N_SCAN_BLKS ((N_NODES + SCAN_BLK - 1) / SCAN_BLK)   // 196
#define NSLICE 8
#define SLICE_NODES (N_NODES / NSLICE)   // 6250 exactly
#define FILL_BLKS_PER_SLICE 256

typedef __attribute__((ext_vector_type(4))) float f32x4;
typedef __attribute__((ext_vector_type(8))) short bf16x8;   // 8 bf16 = 4 VGPRs

__device__ __forceinline__ float bf2f(unsigned short u) {
    unsigned int x = ((unsigned int)u) << 16;
    return __uint_as_float(x);
}
__device__ __forceinline__ unsigned short f2bf(float f) {
    unsigned int x = __float_as_uint(f);
    unsigned int lsb = (x >> 16) & 1u;
    x += 0x7fffu + lsb;
    return (unsigned short)(x >> 16);
}

__global__ void zero_deg_kernel(int* deg) {
    int i = blockIdx.x * blockDim.x + threadIdx.x;
    if (i < N_NODES) deg[i] = 0;
}

__global__ void count_deg_kernel(const int* __restrict__ dst, int* __restrict__ deg) {
    int e = blockIdx.x * blockDim.x + threadIdx.x;
    if (e < N_EDGES) atomicAdd(&deg[dst[e]], 1);
}

__global__ __launch_bounds__(SCAN_BLK) void scan1_kernel(const int* __restrict__ deg,
                                                         int* __restrict__ local,
                                                         int* __restrict__ bsum) {
    __shared__ int buf[SCAN_BLK];
    int tid = threadIdx.x;
    int i = blockIdx.x * SCAN_BLK + tid;
    int v = (i < N_NODES) ? deg[i] : 0;
    buf[tid] = v;
    __syncthreads();
#pragma unroll
    for (int off = 1; off < SCAN_BLK; off <<= 1) {
        int t = (tid >= off) ? buf[tid - off] : 0;
        __syncthreads();
        buf[tid] += t;
        __syncthreads();
    }
    if (i < N_NODES) local[i] = buf[tid] - v;
    if (tid == SCAN_BLK - 1) bsum[blockIdx.x] = buf[tid];
}

__global__ __launch_bounds__(SCAN_BLK) void scan2_kernel(int* __restrict__ bsum,
                                                         int* __restrict__ row_ptr) {
    __shared__ int buf[SCAN_BLK];
    int tid = threadIdx.x;
    int v = (tid < N_SCAN_BLKS) ? bsum[tid] : 0;
    buf[tid] = v;
    __syncthreads();
#pragma unroll
    for (int off = 1; off < SCAN_BLK; off <<= 1) {
        int t = (tid >= off) ? buf[tid - off] : 0;
        __syncthreads();
        buf[tid] += t;
        __syncthreads();
    }
    if (tid < N_SCAN_BLKS) bsum[tid] = buf[tid] - v;
    if (tid == SCAN_BLK - 1) row_ptr[N_NODES] = buf[tid];
}

__global__ __launch_bounds__(SCAN_BLK) void scan3_kernel(const int* __restrict__ deg,
                                                         const int* __restrict__ local,
                                                         const int* __restrict__ bsum,
                                                         int* __restrict__ row_ptr,
                                                         int* __restrict__ cursor,
                                                         float* __restrict__ inv_deg) {
    int i = blockIdx.x * SCAN_BLK + threadIdx.x;
    if (i < N_NODES) {
        int rp = local[i] + bsum[blockIdx.x];
        row_ptr[i] = rp;
        cursor[i] = rp;
        inv_deg[i] = 1.0f / fmaxf((float)deg[i], 1.0f);
    }
}

// XCD-sliced CSR fill: slice = blockIdx & 7 -> (round-robin dispatch) one XCD per slice.
// 2048 blocks (8/CU) for full occupancy to hide the load->atomic latency chain.
__global__ __launch_bounds__(256) void fill_csr_sliced_kernel(const int* __restrict__ src,
                                                              const int* __restrict__ dst,
                                                              int* __restrict__ cursor,
                                                              int* __restrict__ csr_src) {
    int slice = blockIdx.x & (NSLICE - 1);
    int bid = blockIdx.x >> 3;              // block index within slice
    int lo = slice * SLICE_NODES, hi = lo + SLICE_NODES;
    int stride = FILL_BLKS_PER_SLICE * 256;
    for (int e = bid * 256 + threadIdx.x; e < N_EDGES; e += stride) {
        int d = dst[e];
        if (d >= lo && d < hi) {
            int p = atomicAdd(&cursor[d], 1);
            csr_src[p] = src[e];
        }
    }
}

// Pack GEMM-A weights into MFMA B-fragment order (bf16).
// Bpk[((ct*4+kb)*64+l)*8+j] = W[k][c], k=kb*32+(l>>4)*8+j, c=ct*16+(l&15).
// Logical W[128][256] = [W_self0 | W_neigh0].
__global__ void pack_w0_kernel(const float* __restrict__ Ws, const float* __restrict__ Wn,
                               unsigned short* __restrict__ Bpk) {
    int i = blockIdx.x * blockDim.x + threadIdx.x;
    if (i >= 128 * 256) return;
    int j = i & 7, l = (i >> 3) & 63, kb = (i >> 9) & 3, ct = i >> 11;
    int k = kb * 32 + (l >> 4) * 8 + j;
    int c = ct * 16 + (l & 15);
    float v = (c < F) ? Ws[k * F + c] : Wn[k * F + (c - F)];
    Bpk[i] = f2bf(v);
}

// Pack GEMM-B weights: logical W[128][128], cols 0..40 = W_self1, 64..104 = W_neigh1, else 0.
__global__ void pack_w1_kernel(const float* __restrict__ Ws, const float* __restrict__ Wn,
                               unsigned short* __restrict__ Bpk) {
    int i = blockIdx.x * blockDim.x + threadIdx.x;
    if (i >= 128 * 128) return;
    int j = i & 7, l = (i >> 3) & 63, kb = (i >> 9) & 3, ct = i >> 11;
    int k = kb * 32 + (l >> 4) * 8 + j;
    int c = ct * 16 + (l & 15);
    float v = 0.0f;
    if (c < 48) { if (c < NC) v = Ws[k * NC + c]; }
    else if (c >= 64 && c < 112) { int cc = c - 64; if (cc < NC) v = Wn[k * NC + cc]; }
    Bpk[i] = f2bf(v);
}

// MFMA GEMM: C[M][4*CT*16] = A[M][128] @ W. 64-row tile/block, 4 waves, wave covers CT*16 cols.
// AF32: A is fp32 (converted to bf16 during LDS staging); else A is bf16.
// MODE 0: write all cols bf16 to outA[M][CT*64].
// MODE 1 (CT=2): cols<48 -> outA[M][48], 64<=c<112 -> outB[M][48] (both bf16).
template<bool AF32, int CT, int MODE>
__global__ __launch_bounds__(256) void gemm_mfma_kernel(const void* __restrict__ Av,
                                                        const unsigned short* __restrict__ Bpk,
                                                        int M,
                                                        unsigned short* __restrict__ outA,
                                                        unsigned short* __restrict__ outB) {
    __shared__ unsigned short As[64 * 128];  // bf16, XOR-swizzled: idx ^= (row&7)<<3
    int tid = threadIdx.x;
    int wave = tid >> 6, lane = tid & 63;
    int row0 = blockIdx.x * 64;

    if (AF32) {
        const float* A = (const float*)Av;
#pragma unroll
        for (int i = 0; i < 8; ++i) {
            int fid = tid + i * 256;            // float4 id: 2048 total (64 rows x 32)
            int row = fid >> 5, c4 = (fid & 31) * 4;
            int grow = row0 + row; if (grow > M - 1) grow = M - 1;
            f32x4 v = *(const f32x4*)(A + (size_t)grow * F + c4);
            unsigned int p0 = (unsigned)f2bf(v.x) | ((unsigned)f2bf(v.y) << 16);
            unsigned int p1 = (unsigned)f2bf(v.z) | ((unsigned)f2bf(v.w) << 16);
            int idx = (row * 128 + c4) ^ ((row & 7) << 3);
            *(uint2*)&As[idx] = make_uint2(p0, p1);
        }
    } else {
        const unsigned short* A = (const unsigned short*)Av;
#pragma unroll
        for (int i = 0; i < 4; ++i) {
            int fid = tid + i * 256;            // uint4 id: 1024 total (64 rows x 16 chunks of 8 bf16)
            int row = fid >> 4, c8 = (fid & 15) * 8;
            int grow = row0 + row; if (grow > M - 1) grow = M - 1;
            uint4 v = *(const uint4*)&A[(size_t)grow * F + c8];
            int idx = (row * 128 + c8) ^ ((row & 7) << 3);
            *(uint4*)&As[idx] = v;
        }
    }
    __syncthreads();

    f32x4 acc[4][CT];
#pragma unroll
    for (int m = 0; m < 4; ++m)
#pragma unroll
        for (int n = 0; n < CT; ++n) acc[m][n] = (f32x4){0.f, 0.f, 0.f, 0.f};

#pragma unroll
    for (int kb = 0; kb < 4; ++kb) {
        bf16x8 afr[4];
#pragma unroll
        for (int m = 0; m < 4; ++m) {
            int row = m * 16 + (lane & 15);
            int ke = kb * 32 + (lane >> 4) * 8;
            int idx = (row * 128 + ke) ^ ((row & 7) << 3);
            afr[m] = *(const bf16x8*)&As[idx];
        }
#pragma unroll
        for (int n = 0; n < CT; ++n) {
            int ct = wave * CT + n;
            bf16x8 bfr = *(const bf16x8*)&Bpk[((ct * 4 + kb) * 64 + lane) * 8];
#pragma unroll
            for (int m = 0; m < 4; ++m)
                acc[m][n] = __builtin_amdgcn_mfma_f32_16x16x32_bf16(afr[m], bfr, acc[m][n], 0, 0, 0);
        }
    }

#pragma unroll
    for (int m = 0; m < 4; ++m) {
#pragma unroll
        for (int i = 0; i < 4; ++i) {
            int r = row0 + m * 16 + (lane >> 4) * 4 + i;
            if (r < M) {
#pragma unroll
                for (int n = 0; n < CT; ++n) {
                    int c = (wave * CT + n) * 16 + (lane & 15);
                    unsigned short val = f2bf(acc[m][n][i]);
                    if (MODE == 0) {
                        outA[(size_t)r * (CT * 64) + c] = val;
                    } else {
                        if (c < 48) outA[(size_t)r * 48 + c] = val;
                        else if (c >= 64 && c < 112) outB[(size_t)r * 48 + (c - 64)] = val;
                    }
                }
            }
        }
    }
}

// h[node] = relu(u_self + mean(u_neigh) + b0); u is bf16 [N][256] (self 0..127, neigh 128..255).
// 4 waves/block, wave = one node, lane t = 2 cols; edge loop unrolled x4 (4 gathers in flight).
__global__ __launch_bounds__(256) void agg0_kernel(const unsigned int* __restrict__ u,
                                                   const int* __restrict__ row_ptr,
                                                   const int* __restrict__ csr_src,
                                                   const float* __restrict__ inv_deg,
                                                   const float* __restrict__ b0,
                                                   unsigned int* __restrict__ hu) {
    int node = blockIdx.x * 4 + (threadIdx.x >> 6);
    int t = threadIdx.x & 63;
    int s = row_ptr[node], e = row_ptr[node + 1];
    float ax = 0.f, ay = 0.f, bx = 0.f, by = 0.f;
    int j = s;
    for (; j + 3 < e; j += 4) {
        int sr0 = csr_src[j], sr1 = csr_src[j + 1];
        int sr2 = csr_src[j + 2], sr3 = csr_src[j + 3];
        unsigned int v0 = u[(size_t)sr0 * 128 + 64 + t];
        unsigned int v1 = u[(size_t)sr1 * 128 + 64 + t];
        unsigned int v2 = u[(size_t)sr2 * 128 + 64 + t];
        unsigned int v3 = u[(size_t)sr3 * 128 + 64 + t];
        ax += bf2f((unsigned short)(v0 & 0xffffu)) + bf2f((unsigned short)(v1 & 0xffffu));
        ay += bf2f((unsigned short)(v0 >> 16)) + bf2f((unsigned short)(v1 >> 16));
        bx += bf2f((unsigned short)(v2 & 0xffffu)) + bf2f((unsigned short)(v3 & 0xffffu));
        by += bf2f((unsigned short)(v2 >> 16)) + bf2f((unsigned short)(v3 >> 16));
    }
    for (; j < e; ++j) {
        int sr = csr_src[j];
        unsigned int v = u[(size_t)sr * 128 + 64 + t];
        ax += bf2f((unsigned short)(v & 0xffffu));
        ay += bf2f((unsigned short)(v >> 16));
    }
    ax += bx; ay += by;
    float inv = inv_deg[node];
    unsigned int vs = u[(size_t)node * 128 + t];
    float2 bb = ((const float2*)b0)[t];
    float h0 = fmaxf(bf2f((unsigned short)(vs & 0xffffu)) + ax * inv + bb.x, 0.0f);
    float h1 = fmaxf(bf2f((unsigned short)(vs >> 16)) + ay * inv + bb.y, 0.0f);
    hu[(size_t)node * 64 + t] = (unsigned)f2bf(h0) | ((unsigned)f2bf(h1) << 16);
}

// out[node][c] = t_self[node][c] + b1[c] + mean(t_neigh[src][c]); t_* bf16 [N][48].
// 4 waves/block, wave = one node. Wave split into two 32-lane groups handling alternating
// edges (cols = 24 uints); combined at the end via __shfl from lane+32.
__global__ __launch_bounds__(256) void final_out_kernel(const unsigned int* __restrict__ ts,
                                                        const unsigned int* __restrict__ tn,
                                                        const int* __restrict__ row_ptr,
                                                        const int* __restrict__ csr_src,
                                                        const float* __restrict__ inv_deg,
                                                        const float* __restrict__ b1,
                                                        float* __restrict__ out) {
    int node = blockIdx.x * 4 + (threadIdx.x >> 6);
    int lane = threadIdx.x & 63;
    int group = lane >> 5;       // 0 or 1
    int c = lane & 31;           // col-pair index; active c<24 (stray loads land in pad)
    int s = row_ptr[node], e = row_ptr[node + 1];
    float ax = 0.f, ay = 0.f;
    for (int j = s + group; j < e; j += 2) {
        int sr = csr_src[j];
        unsigned int v = tn[(size_t)sr * 24 + c];
        ax += bf2f((unsigned short)(v & 0xffffu));
        ay += bf2f((unsigned short)(v >> 16));
    }
    // combine the two groups: lane<32 pulls group-1 partial from lane+32
    ax += __shfl(ax, lane + 32, 64);
    ay += __shfl(ay, lane + 32, 64);
    if (lane >= 24) return;
    float inv = inv_deg[node];
    unsigned int vs = ts[(size_t)node * 24 + c];
    int c0 = 2 * c, c1 = 2 * c + 1;
    if (c0 < NC)
        out[(size_t)node * NC + c0] = bf2f((unsigned short)(vs & 0xffffu)) + b1[c0] + ax * inv;
    if (c1 < NC)
        out[(size_t)node * NC + c1] = bf2f((unsigned short)(vs >> 16)) + b1[c1] + ay * inv;
}

extern "C" void kernel_launch(void* const* d_in, const int* in_sizes, int n_in,
                              void* d_out, int out_size, void* d_ws, size_t ws_size,
                              hipStream_t stream) {
    const float* x   = (const float*)d_in[0];
    const int*   src = (const int*)d_in[1];
    const int*   dst = (const int*)d_in[2];
    const float* Ws0 = (const float*)d_in[3];
    const float* Wn0 = (const float*)d_in[4];
    const float* b0  = (const float*)d_in[5];
    const float* Ws1 = (const float*)d_in[6];
    const float* Wn1 = (const float*)d_in[7];
    const float* b1  = (const float*)d_in[8];
    float* out = (float*)d_out;

    char* ws = (char*)d_ws;
    size_t o = 0;
    auto alloc = [&](size_t bytes) {
        size_t r = o;
        o = (o + bytes + 255) & ~(size_t)255;
        return r;
    };
    int*   deg     = (int*)(ws + alloc(sizeof(int) * N_NODES));
    int*   local   = (int*)(ws + alloc(sizeof(int) * N_NODES));
    int*   bsum    = (int*)(ws + alloc(sizeof(int) * N_SCAN_BLKS));
    int*   row_ptr = (int*)(ws + alloc(sizeof(int) * (N_NODES + 1)));
    int*   cursor  = (int*)(ws + alloc(sizeof(int) * N_NODES));
    int*   csr     = (int*)(ws + alloc(sizeof(int) * N_EDGES));
    float* inv_deg = (float*)(ws + alloc(sizeof(float) * N_NODES));
    unsigned short* Bpk0 = (unsigned short*)(ws + alloc(sizeof(short) * 128 * 256));
    unsigned short* Bpk1 = (unsigned short*)(ws + alloc(sizeof(short) * 128 * 128));
    unsigned short* u    = (unsigned short*)(ws + alloc(sizeof(short) * (size_t)N_NODES * 256));
    unsigned short* h    = (unsigned short*)(ws + alloc(sizeof(short) * (size_t)N_NODES * 128));
    unsigned short* t_self  = (unsigned short*)(ws + alloc(sizeof(short) * (size_t)N_NODES * 48));
    unsigned short* t_neigh = (unsigned short*)(ws + alloc(sizeof(short) * ((size_t)N_NODES * 48 + 128)));  // +pad for stray lane reads

    zero_deg_kernel<<<(N_NODES + 255) / 256, 256, 0, stream>>>(deg);
    count_deg_kernel<<<(N_EDGES + 255) / 256, 256, 0, stream>>>(dst, deg);
    scan1_kernel<<<N_SCAN_BLKS, SCAN_BLK, 0, stream>>>(deg, local, bsum);
    scan2_kernel<<<1, SCAN_BLK, 0, stream>>>(bsum, row_ptr);
    scan3_kernel<<<N_SCAN_BLKS, SCAN_BLK, 0, stream>>>(deg, local, bsum, row_ptr, cursor, inv_deg);
    fill_csr_sliced_kernel<<<NSLICE * FILL_BLKS_PER_SLICE, 256, 0, stream>>>(src, dst, cursor, csr);
    pack_w0_kernel<<<(128 * 256 + 255) / 256, 256, 0, stream>>>(Ws0, Wn0, Bpk0);
    pack_w1_kernel<<<(128 * 128 + 255) / 256, 256, 0, stream>>>(Ws1, Wn1, Bpk1);

    int nblk = (N_NODES + 63) / 64;  // 782
    // GEMM A: u = bf16(x) @ [Ws0|Wn0]  -> u bf16 [N][256]
    gemm_mfma_kernel<true, 4, 0><<<nblk, 256, 0, stream>>>(x, Bpk0, N_NODES, u, nullptr);
    // agg0: h = relu(u_self + mean(u_neigh) + b0) -> bf16 [N][128]
    agg0_kernel<<<N_NODES / 4, 256, 0, stream>>>((const unsigned int*)u, row_ptr, csr, inv_deg, b0,
                                                 (unsigned int*)h);
    // GEMM B: t = h @ Wcat1 -> t_self bf16[N][48], t_neigh bf16[N][48]
    gemm_mfma_kernel<false, 2, 1><<<nblk, 256, 0, stream>>>(h, Bpk1, N_NODES, t_self, t_neigh);
    // final: out = t_self + b1 + mean(t_neigh)
    final_out_kernel<<<N_NODES / 4, 256, 0, stream>>>((const unsigned int*)t_self,
                                                      (const unsigned int*)t_neigh,
                                                      row_ptr, csr, inv_deg, b1, out);
}

// Round 12
// 262.625 us; speedup vs baseline: 1.2359x; 1.0611x over previous
//
#include <hip/hip_runtime.h>
#include <hip/hip_bf16.h>

#define N_NODES 50000
#define N_EDGES 800000
#define F 128
#define NC 41
#define SCAN_BLK 256
#define N_SCAN_BLKS ((N_NODES + SCAN_BLK - 1) / SCAN_BLK)   // 196
#define NSLICE 8
#define SLICE_NODES (N_NODES / NSLICE)   // 6250 exactly
#define FILL_BLKS_PER_SLICE 256

typedef __attribute__((ext_vector_type(4))) float f32x4;
typedef __attribute__((ext_vector_type(8))) short bf16x8;   // 8 bf16 = 4 VGPRs

__device__ __forceinline__ float bf2f(unsigned short u) {
    unsigned int x = ((unsigned int)u) << 16;
    return __uint_as_float(x);
}
__device__ __forceinline__ unsigned short f2bf(float f) {
    unsigned int x = __float_as_uint(f);
    unsigned int lsb = (x >> 16) & 1u;
    x += 0x7fffu + lsb;
    return (unsigned short)(x >> 16);
}

__global__ void zero_deg_kernel(int* deg) {
    int i = blockIdx.x * blockDim.x + threadIdx.x;
    if (i < N_NODES) deg[i] = 0;
}

__global__ void count_deg_kernel(const int* __restrict__ dst, int* __restrict__ deg) {
    int e = blockIdx.x * blockDim.x + threadIdx.x;
    if (e < N_EDGES) atomicAdd(&deg[dst[e]], 1);
}

__global__ __launch_bounds__(SCAN_BLK) void scan1_kernel(const int* __restrict__ deg,
                                                         int* __restrict__ local,
                                                         int* __restrict__ bsum) {
    __shared__ int buf[SCAN_BLK];
    int tid = threadIdx.x;
    int i = blockIdx.x * SCAN_BLK + tid;
    int v = (i < N_NODES) ? deg[i] : 0;
    buf[tid] = v;
    __syncthreads();
#pragma unroll
    for (int off = 1; off < SCAN_BLK; off <<= 1) {
        int t = (tid >= off) ? buf[tid - off] : 0;
        __syncthreads();
        buf[tid] += t;
        __syncthreads();
    }
    if (i < N_NODES) local[i] = buf[tid] - v;
    if (tid == SCAN_BLK - 1) bsum[blockIdx.x] = buf[tid];
}

__global__ __launch_bounds__(SCAN_BLK) void scan2_kernel(int* __restrict__ bsum,
                                                         int* __restrict__ row_ptr) {
    __shared__ int buf[SCAN_BLK];
    int tid = threadIdx.x;
    int v = (tid < N_SCAN_BLKS) ? bsum[tid] : 0;
    buf[tid] = v;
    __syncthreads();
#pragma unroll
    for (int off = 1; off < SCAN_BLK; off <<= 1) {
        int t = (tid >= off) ? buf[tid - off] : 0;
        __syncthreads();
        buf[tid] += t;
        __syncthreads();
    }
    if (tid < N_SCAN_BLKS) bsum[tid] = buf[tid] - v;
    if (tid == SCAN_BLK - 1) row_ptr[N_NODES] = buf[tid];
}

__global__ __launch_bounds__(SCAN_BLK) void scan3_kernel(const int* __restrict__ deg,
                                                         const int* __restrict__ local,
                                                         const int* __restrict__ bsum,
                                                         int* __restrict__ row_ptr,
                                                         int* __restrict__ cursor,
                                                         float* __restrict__ inv_deg) {
    int i = blockIdx.x * SCAN_BLK + threadIdx.x;
    if (i < N_NODES) {
        int rp = local[i] + bsum[blockIdx.x];
        row_ptr[i] = rp;
        cursor[i] = rp;
        inv_deg[i] = 1.0f / fmaxf((float)deg[i], 1.0f);
    }
}

// XCD-sliced CSR fill: slice = blockIdx & 7 -> (round-robin dispatch) one XCD per slice.
// 2048 blocks (8/CU) for full occupancy to hide the load->atomic latency chain.
__global__ __launch_bounds__(256) void fill_csr_sliced_kernel(const int* __restrict__ src,
                                                              const int* __restrict__ dst,
                                                              int* __restrict__ cursor,
                                                              int* __restrict__ csr_src) {
    int slice = blockIdx.x & (NSLICE - 1);
    int bid = blockIdx.x >> 3;              // block index within slice
    int lo = slice * SLICE_NODES, hi = lo + SLICE_NODES;
    int stride = FILL_BLKS_PER_SLICE * 256;
    for (int e = bid * 256 + threadIdx.x; e < N_EDGES; e += stride) {
        int d = dst[e];
        if (d >= lo && d < hi) {
            int p = atomicAdd(&cursor[d], 1);
            csr_src[p] = src[e];
        }
    }
}

// Pack GEMM-A weights into MFMA B-fragment order (bf16).
// Bpk[((ct*4+kb)*64+l)*8+j] = W[k][c], k=kb*32+(l>>4)*8+j, c=ct*16+(l&15).
// Logical W[128][256] = [W_self0 | W_neigh0].
__global__ void pack_w0_kernel(const float* __restrict__ Ws, const float* __restrict__ Wn,
                               unsigned short* __restrict__ Bpk) {
    int i = blockIdx.x * blockDim.x + threadIdx.x;
    if (i >= 128 * 256) return;
    int j = i & 7, l = (i >> 3) & 63, kb = (i >> 9) & 3, ct = i >> 11;
    int k = kb * 32 + (l >> 4) * 8 + j;
    int c = ct * 16 + (l & 15);
    float v = (c < F) ? Ws[k * F + c] : Wn[k * F + (c - F)];
    Bpk[i] = f2bf(v);
}

// Pack GEMM-B weights: logical W[128][128], cols 0..40 = W_self1, 64..104 = W_neigh1, else 0.
__global__ void pack_w1_kernel(const float* __restrict__ Ws, const float* __restrict__ Wn,
                               unsigned short* __restrict__ Bpk) {
    int i = blockIdx.x * blockDim.x + threadIdx.x;
    if (i >= 128 * 128) return;
    int j = i & 7, l = (i >> 3) & 63, kb = (i >> 9) & 3, ct = i >> 11;
    int k = kb * 32 + (l >> 4) * 8 + j;
    int c = ct * 16 + (l & 15);
    float v = 0.0f;
    if (c < 48) { if (c < NC) v = Ws[k * NC + c]; }
    else if (c >= 64 && c < 112) { int cc = c - 64; if (cc < NC) v = Wn[k * NC + cc]; }
    Bpk[i] = f2bf(v);
}

// MFMA GEMM: C[M][4*CT*16] = A[M][128] @ W. 64-row tile/block, 4 waves, wave covers CT*16 cols.
// AF32: A is fp32 (converted to bf16 during LDS staging); else A is bf16.
// MODE 0: write all cols bf16 to outA[M][CT*64].
// MODE 1 (CT=2): cols<48 -> outA[M][48], 64<=c<112 -> outB[M][48] (both bf16).
template<bool AF32, int CT, int MODE>
__global__ __launch_bounds__(256) void gemm_mfma_kernel(const void* __restrict__ Av,
                                                        const unsigned short* __restrict__ Bpk,
                                                        int M,
                                                        unsigned short* __restrict__ outA,
                                                        unsigned short* __restrict__ outB) {
    __shared__ unsigned short As[64 * 128];  // bf16, XOR-swizzled: idx ^= (row&7)<<3
    int tid = threadIdx.x;
    int wave = tid >> 6, lane = tid & 63;
    int row0 = blockIdx.x * 64;

    if (AF32) {
        const float* A = (const float*)Av;
#pragma unroll
        for (int i = 0; i < 8; ++i) {
            int fid = tid + i * 256;            // float4 id: 2048 total (64 rows x 32)
            int row = fid >> 5, c4 = (fid & 31) * 4;
            int grow = row0 + row; if (grow > M - 1) grow = M - 1;
            f32x4 v = *(const f32x4*)(A + (size_t)grow * F + c4);
            unsigned int p0 = (unsigned)f2bf(v.x) | ((unsigned)f2bf(v.y) << 16);
            unsigned int p1 = (unsigned)f2bf(v.z) | ((unsigned)f2bf(v.w) << 16);
            int idx = (row * 128 + c4) ^ ((row & 7) << 3);
            *(uint2*)&As[idx] = make_uint2(p0, p1);
        }
    } else {
        const unsigned short* A = (const unsigned short*)Av;
#pragma unroll
        for (int i = 0; i < 4; ++i) {
            int fid = tid + i * 256;            // uint4 id: 1024 total (64 rows x 16 chunks of 8 bf16)
            int row = fid >> 4, c8 = (fid & 15) * 8;
            int grow = row0 + row; if (grow > M - 1) grow = M - 1;
            uint4 v = *(const uint4*)&A[(size_t)grow * F + c8];
            int idx = (row * 128 + c8) ^ ((row & 7) << 3);
            *(uint4*)&As[idx] = v;
        }
    }
    __syncthreads();

    f32x4 acc[4][CT];
#pragma unroll
    for (int m = 0; m < 4; ++m)
#pragma unroll
        for (int n = 0; n < CT; ++n) acc[m][n] = (f32x4){0.f, 0.f, 0.f, 0.f};

#pragma unroll
    for (int kb = 0; kb < 4; ++kb) {
        bf16x8 afr[4];
#pragma unroll
        for (int m = 0; m < 4; ++m) {
            int row = m * 16 + (lane & 15);
            int ke = kb * 32 + (lane >> 4) * 8;
            int idx = (row * 128 + ke) ^ ((row & 7) << 3);
            afr[m] = *(const bf16x8*)&As[idx];
        }
#pragma unroll
        for (int n = 0; n < CT; ++n) {
            int ct = wave * CT + n;
            bf16x8 bfr = *(const bf16x8*)&Bpk[((ct * 4 + kb) * 64 + lane) * 8];
#pragma unroll
            for (int m = 0; m < 4; ++m)
                acc[m][n] = __builtin_amdgcn_mfma_f32_16x16x32_bf16(afr[m], bfr, acc[m][n], 0, 0, 0);
        }
    }

#pragma unroll
    for (int m = 0; m < 4; ++m) {
#pragma unroll
        for (int i = 0; i < 4; ++i) {
            int r = row0 + m * 16 + (lane >> 4) * 4 + i;
            if (r < M) {
#pragma unroll
                for (int n = 0; n < CT; ++n) {
                    int c = (wave * CT + n) * 16 + (lane & 15);
                    unsigned short val = f2bf(acc[m][n][i]);
                    if (MODE == 0) {
                        outA[(size_t)r * (CT * 64) + c] = val;
                    } else {
                        if (c < 48) outA[(size_t)r * 48 + c] = val;
                        else if (c >= 64 && c < 112) outB[(size_t)r * 48 + (c - 64)] = val;
                    }
                }
            }
        }
    }
}

// h[node] = relu(u_self + mean(u_neigh) + b0); u is bf16 [N][256] (self 0..127, neigh 128..255).
// 4 waves/block, wave = one node, lane t = 2 cols; edge loop unrolled x4 (4 gathers in flight).
__global__ __launch_bounds__(256) void agg0_kernel(const unsigned int* __restrict__ u,
                                                   const int* __restrict__ row_ptr,
                                                   const int* __restrict__ csr_src,
                                                   const float* __restrict__ inv_deg,
                                                   const float* __restrict__ b0,
                                                   unsigned int* __restrict__ hu) {
    int node = blockIdx.x * 4 + (threadIdx.x >> 6);
    int t = threadIdx.x & 63;
    int s = row_ptr[node], e = row_ptr[node + 1];
    float ax = 0.f, ay = 0.f, bx = 0.f, by = 0.f;
    int j = s;
    for (; j + 3 < e; j += 4) {
        int sr0 = csr_src[j], sr1 = csr_src[j + 1];
        int sr2 = csr_src[j + 2], sr3 = csr_src[j + 3];
        unsigned int v0 = u[(size_t)sr0 * 128 + 64 + t];
        unsigned int v1 = u[(size_t)sr1 * 128 + 64 + t];
        unsigned int v2 = u[(size_t)sr2 * 128 + 64 + t];
        unsigned int v3 = u[(size_t)sr3 * 128 + 64 + t];
        ax += bf2f((unsigned short)(v0 & 0xffffu)) + bf2f((unsigned short)(v1 & 0xffffu));
        ay += bf2f((unsigned short)(v0 >> 16)) + bf2f((unsigned short)(v1 >> 16));
        bx += bf2f((unsigned short)(v2 & 0xffffu)) + bf2f((unsigned short)(v3 & 0xffffu));
        by += bf2f((unsigned short)(v2 >> 16)) + bf2f((unsigned short)(v3 >> 16));
    }
    for (; j < e; ++j) {
        int sr = csr_src[j];
        unsigned int v = u[(size_t)sr * 128 + 64 + t];
        ax += bf2f((unsigned short)(v & 0xffffu));
        ay += bf2f((unsigned short)(v >> 16));
    }
    ax += bx; ay += by;
    float inv = inv_deg[node];
    unsigned int vs = u[(size_t)node * 128 + t];
    float2 bb = ((const float2*)b0)[t];
    float h0 = fmaxf(bf2f((unsigned short)(vs & 0xffffu)) + ax * inv + bb.x, 0.0f);
    float h1 = fmaxf(bf2f((unsigned short)(vs >> 16)) + ay * inv + bb.y, 0.0f);
    hu[(size_t)node * 64 + t] = (unsigned)f2bf(h0) | ((unsigned)f2bf(h1) << 16);
}

// out[node][c] = t_self[node][c] + b1[c] + mean(t_neigh[src][c]); t_* bf16 [N][48].
// 4 waves/block, wave = one node. Wave split into two 32-lane groups handling alternating
// edges; per group the edge loop is unrolled x4 (8 gathers in flight per wave).
__global__ __launch_bounds__(256) void final_out_kernel(const unsigned int* __restrict__ ts,
                                                        const unsigned int* __restrict__ tn,
                                                        const int* __restrict__ row_ptr,
                                                        const int* __restrict__ csr_src,
                                                        const float* __restrict__ inv_deg,
                                                        const float* __restrict__ b1,
                                                        float* __restrict__ out) {
    int node = blockIdx.x * 4 + (threadIdx.x >> 6);
    int lane = threadIdx.x & 63;
    int group = lane >> 5;       // 0 or 1
    int c = lane & 31;           // col-pair index; active c<24 (stray loads land in pad)
    int s = row_ptr[node], e = row_ptr[node + 1];
    float ax = 0.f, ay = 0.f, bx = 0.f, by = 0.f;
    int j = s + group;
    // 4 edges per iteration per group (stride 2 within group): 4 independent gathers in flight
    for (; j + 6 < e; j += 8) {
        int sr0 = csr_src[j], sr1 = csr_src[j + 2];
        int sr2 = csr_src[j + 4], sr3 = csr_src[j + 6];
        unsigned int v0 = tn[(size_t)sr0 * 24 + c];
        unsigned int v1 = tn[(size_t)sr1 * 24 + c];
        unsigned int v2 = tn[(size_t)sr2 * 24 + c];
        unsigned int v3 = tn[(size_t)sr3 * 24 + c];
        ax += bf2f((unsigned short)(v0 & 0xffffu)) + bf2f((unsigned short)(v1 & 0xffffu));
        ay += bf2f((unsigned short)(v0 >> 16)) + bf2f((unsigned short)(v1 >> 16));
        bx += bf2f((unsigned short)(v2 & 0xffffu)) + bf2f((unsigned short)(v3 & 0xffffu));
        by += bf2f((unsigned short)(v2 >> 16)) + bf2f((unsigned short)(v3 >> 16));
    }
    for (; j < e; j += 2) {
        int sr = csr_src[j];
        unsigned int v = tn[(size_t)sr * 24 + c];
        ax += bf2f((unsigned short)(v & 0xffffu));
        ay += bf2f((unsigned short)(v >> 16));
    }
    ax += bx; ay += by;
    // combine the two groups: lane<32 pulls group-1 partial from lane+32
    ax += __shfl(ax, lane + 32, 64);
    ay += __shfl(ay, lane + 32, 64);
    if (lane >= 24) return;
    float inv = inv_deg[node];
    unsigned int vs = ts[(size_t)node * 24 + c];
    int c0 = 2 * c, c1 = 2 * c + 1;
    if (c0 < NC)
        out[(size_t)node * NC + c0] = bf2f((unsigned short)(vs & 0xffffu)) + b1[c0] + ax * inv;
    if (c1 < NC)
        out[(size_t)node * NC + c1] = bf2f((unsigned short)(vs >> 16)) + b1[c1] + ay * inv;
}

extern "C" void kernel_launch(void* const* d_in, const int* in_sizes, int n_in,
                              void* d_out, int out_size, void* d_ws, size_t ws_size,
                              hipStream_t stream) {
    const float* x   = (const float*)d_in[0];
    const int*   src = (const int*)d_in[1];
    const int*   dst = (const int*)d_in[2];
    const float* Ws0 = (const float*)d_in[3];
    const float* Wn0 = (const float*)d_in[4];
    const float* b0  = (const float*)d_in[5];
    const float* Ws1 = (const float*)d_in[6];
    const float* Wn1 = (const float*)d_in[7];
    const float* b1  = (const float*)d_in[8];
    float* out = (float*)d_out;

    char* ws = (char*)d_ws;
    size_t o = 0;
    auto alloc = [&](size_t bytes) {
        size_t r = o;
        o = (o + bytes + 255) & ~(size_t)255;
        return r;
    };
    int*   deg     = (int*)(ws + alloc(sizeof(int) * N_NODES));
    int*   local   = (int*)(ws + alloc(sizeof(int) * N_NODES));
    int*   bsum    = (int*)(ws + alloc(sizeof(int) * N_SCAN_BLKS));
    int*   row_ptr = (int*)(ws + alloc(sizeof(int) * (N_NODES + 1)));
    int*   cursor  = (int*)(ws + alloc(sizeof(int) * N_NODES));
    int*   csr     = (int*)(ws + alloc(sizeof(int) * N_EDGES));
    float* inv_deg = (float*)(ws + alloc(sizeof(float) * N_NODES));
    unsigned short* Bpk0 = (unsigned short*)(ws + alloc(sizeof(short) * 128 * 256));
    unsigned short* Bpk1 = (unsigned short*)(ws + alloc(sizeof(short) * 128 * 128));
    unsigned short* u    = (unsigned short*)(ws + alloc(sizeof(short) * (size_t)N_NODES * 256));
    unsigned short* h    = (unsigned short*)(ws + alloc(sizeof(short) * (size_t)N_NODES * 128));
    unsigned short* t_self  = (unsigned short*)(ws + alloc(sizeof(short) * (size_t)N_NODES * 48));
    unsigned short* t_neigh = (unsigned short*)(ws + alloc(sizeof(short) * ((size_t)N_NODES * 48 + 128)));  // +pad for stray lane reads

    zero_deg_kernel<<<(N_NODES + 255) / 256, 256, 0, stream>>>(deg);
    count_deg_kernel<<<(N_EDGES + 255) / 256, 256, 0, stream>>>(dst, deg);
    scan1_kernel<<<N_SCAN_BLKS, SCAN_BLK, 0, stream>>>(deg, local, bsum);
    scan2_kernel<<<1, SCAN_BLK, 0, stream>>>(bsum, row_ptr);
    scan3_kernel<<<N_SCAN_BLKS, SCAN_BLK, 0, stream>>>(deg, local, bsum, row_ptr, cursor, inv_deg);
    fill_csr_sliced_kernel<<<NSLICE * FILL_BLKS_PER_SLICE, 256, 0, stream>>>(src, dst, cursor, csr);
    pack_w0_kernel<<<(128 * 256 + 255) / 256, 256, 0, stream>>>(Ws0, Wn0, Bpk0);
    pack_w1_kernel<<<(128 * 128 + 255) / 256, 256, 0, stream>>>(Ws1, Wn1, Bpk1);

    int nblk = (N_NODES + 63) / 64;  // 782
    // GEMM A: u = bf16(x) @ [Ws0|Wn0]  -> u bf16 [N][256]
    gemm_mfma_kernel<true, 4, 0><<<nblk, 256, 0, stream>>>(x, Bpk0, N_NODES, u, nullptr);
    // agg0: h = relu(u_self + mean(u_neigh) + b0) -> bf16 [N][128]
    agg0_kernel<<<N_NODES / 4, 256, 0, stream>>>((const unsigned int*)u, row_ptr, csr, inv_deg, b0,
                                                 (unsigned int*)h);
    // GEMM B: t = h @ Wcat1 -> t_self bf16[N][48], t_neigh bf16[N][48]
    gemm_mfma_kernel<false, 2, 1><<<nblk, 256, 0, stream>>>(h, Bpk1, N_NODES, t_self, t_neigh);
    // final: out = t_self + b1 + mean(t_neigh)
    final_out_kernel<<<N_NODES / 4, 256, 0, stream>>>((const unsigned int*)t_self,
                                                      (const unsigned int*)t_neigh,
                                                      row_ptr, csr, inv_deg, b1, out);
}